// Round 1
// baseline (3139.512 us; speedup 1.0000x reference)
//
#include <hip/hip_runtime.h>
#include <math.h>

// ---------------------------------------------------------------------------
// DAGNN: h=relu(nf@W1+b1); logits=h@W2+b2; 20x (x<-A x) with fused gated sum
// out = sum_k sigmoid(x_k . Wg + bg) * x_k    (k=0..20, x_0 = logits)
// A x = segment_sum(ew[:,None] * x[senders], receivers)  -> receiver-CSR, no atomics
// ---------------------------------------------------------------------------

#define F_IN 512
#define C 64  // hidden == n_classes == 64

// ---------- GEMM1: [M,512] @ [512,64] + b1, relu --------------------------
__global__ __launch_bounds__(256) void gemm1_relu(
    const float* __restrict__ A, const float* __restrict__ W1,
    const float* __restrict__ b1, float* __restrict__ H, int M)
{
  __shared__ __align__(16) float As[16][68];  // transposed [k][m], pad to 68
  __shared__ __align__(16) float Bs[16][64];
  int t = threadIdx.x;
  int tx = t & 15, ty = t >> 4;
  int m0 = blockIdx.x * 64;
  int lm = t >> 2, lk = (t & 3) << 2;
  const float* Arow = A + (size_t)(m0 + lm) * F_IN;
  bool aok = (m0 + lm) < M;
  float acc[4][4] = {};

  for (int k0 = 0; k0 < F_IN; k0 += 16) {
    float4 av = make_float4(0.f, 0.f, 0.f, 0.f);
    if (aok) av = *(const float4*)(Arow + k0 + lk);
    float bv[4];
#pragma unroll
    for (int i = 0; i < 4; ++i)
      bv[i] = W1[(size_t)(k0 + (t >> 6) + (i << 2)) * C + (t & 63)];
    __syncthreads();
    As[lk + 0][lm] = av.x; As[lk + 1][lm] = av.y;
    As[lk + 2][lm] = av.z; As[lk + 3][lm] = av.w;
#pragma unroll
    for (int i = 0; i < 4; ++i)
      Bs[(t >> 6) + (i << 2)][t & 63] = bv[i];
    __syncthreads();
#pragma unroll
    for (int kk = 0; kk < 16; ++kk) {
      float4 a = *(const float4*)&As[kk][ty << 2];
      float4 b = *(const float4*)&Bs[kk][tx << 2];
      acc[0][0] += a.x * b.x; acc[0][1] += a.x * b.y; acc[0][2] += a.x * b.z; acc[0][3] += a.x * b.w;
      acc[1][0] += a.y * b.x; acc[1][1] += a.y * b.y; acc[1][2] += a.y * b.z; acc[1][3] += a.y * b.w;
      acc[2][0] += a.z * b.x; acc[2][1] += a.z * b.y; acc[2][2] += a.z * b.z; acc[2][3] += a.z * b.w;
      acc[3][0] += a.w * b.x; acc[3][1] += a.w * b.y; acc[3][2] += a.w * b.z; acc[3][3] += a.w * b.w;
    }
    __syncthreads();
  }
  float4 bb = *(const float4*)&b1[tx << 2];
#pragma unroll
  for (int i = 0; i < 4; ++i) {
    int row = m0 + (ty << 2) + i;
    if (row < M) {
      float4 r;
      r.x = fmaxf(acc[i][0] + bb.x, 0.f);
      r.y = fmaxf(acc[i][1] + bb.y, 0.f);
      r.z = fmaxf(acc[i][2] + bb.z, 0.f);
      r.w = fmaxf(acc[i][3] + bb.w, 0.f);
      *(float4*)&H[(size_t)row * C + (tx << 2)] = r;
    }
  }
}

// ---------- GEMM2 + gate init: logits = h@W2+b2; out = sig(logits.Wg+bg)*logits
__global__ __launch_bounds__(256) void gemm2_gate(
    const float* __restrict__ h, const float* __restrict__ W2,
    const float* __restrict__ b2, const float* __restrict__ Wg,
    const float* __restrict__ bgp, float* __restrict__ logits,
    float* __restrict__ out, int n)
{
  __shared__ float W2s[C * C];
  int t = threadIdx.x;
  for (int i = t; i < C * C; i += blockDim.x) W2s[i] = W2[i];
  __syncthreads();
  int lane = t & 63, wid = t >> 6;
  int wave = blockIdx.x * (blockDim.x >> 6) + wid;
  int nw = gridDim.x * (blockDim.x >> 6);
  float wg = Wg[lane], bgv = bgp[0], b2v = b2[lane];
  for (int node = wave; node < n; node += nw) {
    float hv = h[(size_t)node * C + lane];
    float acc = b2v;
#pragma unroll
    for (int k = 0; k < C; ++k) {
      float hk = __shfl(hv, k, 64);
      acc += hk * W2s[k * C + lane];
    }
    float p = acc * wg;
#pragma unroll
    for (int off = 32; off > 0; off >>= 1) p += __shfl_xor(p, off, 64);
    float g = 1.f / (1.f + expf(-(p + bgv)));
    size_t o = (size_t)node * C + lane;
    logits[o] = acc;
    out[o] = g * acc;
  }
}

// ---------- CSR build -----------------------------------------------------
__global__ void zero_int(int* __restrict__ p, int n) {
  int i = blockIdx.x * blockDim.x + threadIdx.x;
  if (i < n) p[i] = 0;
}

__global__ void hist_recv(const int* __restrict__ recv, int* __restrict__ cnt, int E) {
  int i = blockIdx.x * blockDim.x + threadIdx.x;
  if (i < E) atomicAdd(&cnt[recv[i]], 1);
}

// single-block exclusive scan; writes row_start[0..n] and cursor (aliases cnt)
__global__ __launch_bounds__(1024) void scan_counts(
    int* __restrict__ cnt_cursor, int* __restrict__ row_start, int n)
{
  __shared__ int wsum[16];
  int t = threadIdx.x, lane = t & 63, wid = t >> 6;
  int carry = 0;
  for (int base = 0; base < n; base += 1024) {
    int idx = base + t;
    int v = (idx < n) ? cnt_cursor[idx] : 0;
    int incl = v;
#pragma unroll
    for (int off = 1; off < 64; off <<= 1) {
      int u = __shfl_up(incl, off, 64);
      if (lane >= off) incl += u;
    }
    if (lane == 63) wsum[wid] = incl;
    __syncthreads();
    if (t < 16) {
      int ws = wsum[t];
#pragma unroll
      for (int off = 1; off < 16; off <<= 1) {
        int u = __shfl_up(ws, off, 16);
        if ((t & 15) >= off) ws += u;
      }
      wsum[t] = ws;
    }
    __syncthreads();
    int woff = (wid > 0) ? wsum[wid - 1] : 0;
    int total = wsum[15];
    int excl = carry + woff + (incl - v);
    if (idx < n) { row_start[idx] = excl; cnt_cursor[idx] = excl; }
    carry += total;
    __syncthreads();
  }
  if (t == 0) row_start[n] = carry;
}

__global__ void scatter_edges(
    const int* __restrict__ send, const int* __restrict__ recv,
    const float* __restrict__ ew, int* __restrict__ cursor,
    int* __restrict__ cs, float* __restrict__ cw, int E)
{
  int i = blockIdx.x * blockDim.x + threadIdx.x;
  if (i < E) {
    int r = recv[i];
    int p = atomicAdd(&cursor[r], 1);
    cs[p] = send[i];
    cw[p] = ew[i];
  }
}

// ---------- fused SpMM + gate accumulate ----------------------------------
// wave per receiver node, lane = channel. x_next[r] = sum_e w_e x[s_e];
// out[r] += sigmoid(x_next[r].Wg + bg) * x_next[r]
__global__ __launch_bounds__(256) void spmm_gate(
    const float* __restrict__ x, const int* __restrict__ row_start,
    const int* __restrict__ cs, const float* __restrict__ cw,
    const float* __restrict__ Wg, const float* __restrict__ bgp,
    float* __restrict__ x_next, float* __restrict__ out, int n)
{
  int t = threadIdx.x;
  int lane = t & 63, wid = t >> 6;
  int wave = blockIdx.x * (blockDim.x >> 6) + wid;
  int nw = gridDim.x * (blockDim.x >> 6);
  float wg = Wg[lane], bgv = bgp[0];

  for (int node = wave; node < n; node += nw) {
    int beg = row_start[node], end = row_start[node + 1];
    float a0 = 0.f, a1 = 0.f, a2 = 0.f, a3 = 0.f;
    for (int base = beg; base < end; base += 64) {
      int sv = 0; float wv = 0.f;
      if (base + lane < end) { sv = cs[base + lane]; wv = cw[base + lane]; }
      int cnt = end - base; if (cnt > 64) cnt = 64;
      int j = 0;
      for (; j + 4 <= cnt; j += 4) {
        int s0 = __shfl(sv, j, 64), s1 = __shfl(sv, j + 1, 64);
        int s2 = __shfl(sv, j + 2, 64), s3 = __shfl(sv, j + 3, 64);
        float w0 = __shfl(wv, j, 64), w1 = __shfl(wv, j + 1, 64);
        float w2 = __shfl(wv, j + 2, 64), w3 = __shfl(wv, j + 3, 64);
        float v0 = x[(size_t)s0 * C + lane];
        float v1 = x[(size_t)s1 * C + lane];
        float v2 = x[(size_t)s2 * C + lane];
        float v3 = x[(size_t)s3 * C + lane];
        a0 += w0 * v0; a1 += w1 * v1; a2 += w2 * v2; a3 += w3 * v3;
      }
      for (; j < cnt; ++j) {
        int sj = __shfl(sv, j, 64);
        float wj = __shfl(wv, j, 64);
        a0 += wj * x[(size_t)sj * C + lane];
      }
    }
    float acc = (a0 + a1) + (a2 + a3);
    float p = acc * wg;
#pragma unroll
    for (int off = 32; off > 0; off >>= 1) p += __shfl_xor(p, off, 64);
    float g = 1.f / (1.f + expf(-(p + bgv)));
    size_t o = (size_t)node * C + lane;
    x_next[o] = acc;
    out[o] += g * acc;
  }
}

// ---------------------------------------------------------------------------
extern "C" void kernel_launch(void* const* d_in, const int* in_sizes, int n_in,
                              void* d_out, int out_size, void* d_ws, size_t ws_size,
                              hipStream_t stream) {
  const float* nf   = (const float*)d_in[0];
  const float* ew   = (const float*)d_in[1];
  const float* W1   = (const float*)d_in[2];
  const float* b1   = (const float*)d_in[3];
  const float* W2   = (const float*)d_in[4];
  const float* b2   = (const float*)d_in[5];
  const float* Wg   = (const float*)d_in[6];
  const float* bg   = (const float*)d_in[7];
  const int* send   = (const int*)d_in[8];
  const int* recv   = (const int*)d_in[9];
  float* out = (float*)d_out;

  int n = in_sizes[0] / F_IN;     // 100000
  int E = in_sizes[1];            // 3200000

  // workspace layout (floats/ints, 4B each)
  float* buf0 = (float*)d_ws;                       // n*64: logits / x even
  float* buf1 = buf0 + (size_t)n * C;               // n*64: h, then x odd
  int*   csr_s = (int*)(buf1 + (size_t)n * C);      // E
  float* csr_w = (float*)(csr_s + E);               // E
  int*   row_start = (int*)(csr_w + E);             // n+1
  int*   cursor = row_start + (n + 1);              // n  (also histogram cnt)

  // 1) h = relu(nf@W1+b1)  -> buf1
  gemm1_relu<<<(n + 63) / 64, 256, 0, stream>>>(nf, W1, b1, buf1, n);

  // 2) logits = h@W2+b2 -> buf0 ; out = sig(logits.Wg+bg)*logits
  gemm2_gate<<<(n + 3) / 4, 256, 0, stream>>>(buf1, W2, b2, Wg, bg, buf0, out, n);

  // 3) CSR build (receiver-major)
  zero_int<<<(n + 255) / 256, 256, 0, stream>>>(cursor, n);
  hist_recv<<<(E + 255) / 256, 256, 0, stream>>>(recv, cursor, E);
  scan_counts<<<1, 1024, 0, stream>>>(cursor, row_start, n);
  scatter_edges<<<(E + 255) / 256, 256, 0, stream>>>(send, recv, ew, cursor,
                                                     csr_s, csr_w, E);

  // 4) 20 propagation hops, gate-fused. x ping-pongs buf0 <-> buf1.
  float* xin = buf0;
  float* xout = buf1;
  for (int k = 0; k < 20; ++k) {
    spmm_gate<<<(n + 3) / 4, 256, 0, stream>>>(xin, row_start, csr_s, csr_w,
                                               Wg, bg, xout, out, n);
    float* tmp = xin; xin = xout; xout = tmp;
  }
}